// Round 8
// baseline (195.387 us; speedup 1.0000x reference)
//
#include <hip/hip_runtime.h>

#define HF 64
#define WF 64
#define CCH 512

typedef float f32x4 __attribute__((ext_vector_type(4)));

// f32 -> bf16 round-to-nearest-even
__device__ __forceinline__ unsigned short f32_to_bf16(float f) {
    unsigned int x = __float_as_uint(f);
    unsigned int r = (x + 0x7FFFu + ((x >> 16) & 1u)) >> 16;
    return (unsigned short)r;
}
__device__ __forceinline__ float bf16_to_f32(unsigned short u) {
    return __uint_as_float(((unsigned int)u) << 16);
}

// ---------------- transpose+convert NCHW f32 -> NHWC bf16 -------------------
__global__ __launch_bounds__(256) void nchw_to_nhwc_bf16(const float* __restrict__ src,
                                                         unsigned short* __restrict__ dst) {
    __shared__ float tile[32][33];
    const int hw0 = blockIdx.x * 32;
    const int c0  = blockIdx.y * 32;
    const int b   = blockIdx.z;
    const int tx  = threadIdx.x & 31;
    const int ty  = threadIdx.x >> 5;   // 0..7
    const float*    s = src + (size_t)b * CCH * (HF * WF);
    unsigned short* d = dst + (size_t)b * (HF * WF) * CCH;
#pragma unroll
    for (int i = 0; i < 32; i += 8)
        tile[ty + i][tx] = s[(size_t)(c0 + ty + i) * (HF * WF) + hw0 + tx];
    __syncthreads();
#pragma unroll
    for (int i = 0; i < 32; i += 8)
        d[(size_t)(hw0 + ty + i) * CCH + c0 + tx] = f32_to_bf16(tile[tx][ty + i]);
}

// ---------------- main RoIAlign+avg kernel (NHWC bf16 gather) ---------------
// One block = (roi k, channel chunk of 256). Thread = one channel.
// R8 single lever vs R7: occupancy. LDS staging removed entirely (the 50 KB
// tile capped the CU at 12 waves; LDS-per-wave is invariant under any
// channel-split, so shrinking tiles can't help). Output rows store directly
// from registers: thread t's 49 floats are contiguous at base+t*196B, so a
// wave's stores cover a contiguous 12.5 KB region -> L2 merges full lines.
// __launch_bounds__(256,4) caps VGPR at 128 -> 16 waves/CU.
// NOTE (R5): never stage output as bf16 in LDS (73->444us, mechanism unknown).
__global__ __launch_bounds__(256, 4) void roialign_bf16(const unsigned short* __restrict__ ft,
                                                        const float* __restrict__ rois,
                                                        float* __restrict__ out) {
    const int blk   = blockIdx.x;
    const int k     = blk >> 1;
    const int chunk = blk & 1;
    const int tid   = threadIdx.x;
    const int c     = chunk * 256 + tid;

    const float* r = rois + (size_t)k * 5;
    const int   b  = (int)r[0];
    const float x1 = r[1] * 0.0625f;
    const float y1 = r[2] * 0.0625f;
    const float x2 = r[3] * 0.0625f;
    const float y2 = r[4] * 0.0625f;
    const float bin_h = fmaxf(y2 - y1, 0.0f) / 7.0f;
    const float bin_w = fmaxf(x2 - x1, 0.0f) / 7.0f;

    int   hi_[8]; float hr_[8]; float fvh[8];
    int   wi_[8]; float wr_[8]; float fvw[8];
#pragma unroll
    for (int i = 0; i < 8; ++i) {
        float h  = y1 + (float)i * bin_h;
        float hs = fminf(floorf(h), 62.0f);
        hr_[i]   = h - hs;
        hi_[i]   = (int)fminf(fmaxf(hs, 0.0f), 62.0f);
        fvh[i]   = (h >= 0.0f && h < 64.0f) ? 1.0f : 0.0f;
        float w  = x1 + (float)i * bin_w;
        float ws = fminf(floorf(w), 62.0f);
        wr_[i]   = w - ws;
        wi_[i]   = (int)fminf(fmaxf(ws, 0.0f), 62.0f);
        fvw[i]   = (w >= 0.0f && w < 64.0f) ? 1.0f : 0.0f;
    }

    float  prev[8];
    float* obase = out + ((size_t)k * CCH + (size_t)c) * 49;  // this thread's 49-float run

#pragma unroll
    for (int i = 0; i < 8; ++i) {
        float cur[8];
#pragma unroll
        for (int j = 0; j < 8; ++j) {
            const unsigned int o00 =
                (unsigned int)(((b * HF + hi_[i]) * WF + wi_[j]) * CCH + c);
            const float v00 = bf16_to_f32(ft[o00]);
            const float v01 = bf16_to_f32(ft[o00 + CCH]);
            const float v10 = bf16_to_f32(ft[o00 + WF * CCH]);
            const float v11 = bf16_to_f32(ft[o00 + WF * CCH + CCH]);
            const float top = v00 + wr_[j] * (v01 - v00);
            const float bot = v10 + wr_[j] * (v11 - v10);
            const float v   = top + hr_[i] * (bot - top);
            cur[j] = v * (fvh[i] * fvw[j]);
        }
        if (i > 0) {
#pragma unroll
            for (int j = 0; j < 7; ++j)
                obase[(i - 1) * 7 + j] =
                    0.25f * (prev[j] + prev[j + 1] + cur[j] + cur[j + 1]);
        }
#pragma unroll
        for (int j = 0; j < 8; ++j) prev[j] = cur[j];
    }
}

// ---------------- fallback: direct NCHW f32 (if ws too small) ---------------
__global__ __launch_bounds__(256) void roialign_f32_nchw(const float* __restrict__ ft,
                                                         const float* __restrict__ rois,
                                                         float* __restrict__ out) {
    __shared__ __align__(16) float sbuf[256 * 49];
    const int blk   = blockIdx.x;
    const int k     = blk >> 1;
    const int chunk = blk & 1;
    const int tid   = threadIdx.x;
    const int c     = chunk * 256 + tid;

    const float* r = rois + (size_t)k * 5;
    const int   b  = (int)r[0];
    const float x1 = r[1] * 0.0625f;
    const float y1 = r[2] * 0.0625f;
    const float x2 = r[3] * 0.0625f;
    const float y2 = r[4] * 0.0625f;
    const float bin_h = fmaxf(y2 - y1, 0.0f) / 7.0f;
    const float bin_w = fmaxf(x2 - x1, 0.0f) / 7.0f;

    int hi_[8]; float hr_[8]; float fvh[8];
    int wi_[8]; float wr_[8]; float fvw[8];
#pragma unroll
    for (int i = 0; i < 8; ++i) {
        float h  = y1 + (float)i * bin_h;
        float hs = fminf(floorf(h), 62.0f);
        hr_[i] = h - hs;
        hi_[i] = (int)fminf(fmaxf(hs, 0.0f), 62.0f);
        fvh[i] = (h >= 0.0f && h < 64.0f) ? 1.0f : 0.0f;
        float w  = x1 + (float)i * bin_w;
        float ws = fminf(floorf(w), 62.0f);
        wr_[i] = w - ws;
        wi_[i] = (int)fminf(fmaxf(ws, 0.0f), 62.0f);
        fvw[i] = (w >= 0.0f && w < 64.0f) ? 1.0f : 0.0f;
    }

    float prev[8];
    float* srow = sbuf + tid * 49;
#pragma unroll
    for (int i = 0; i < 8; ++i) {
        float cur[8];
#pragma unroll
        for (int j = 0; j < 8; ++j) {
            size_t o00 = (size_t)(b * CCH + c) * (HF * WF) + hi_[i] * WF + wi_[j];
            const float v00 = ft[o00];
            const float v01 = ft[o00 + 1];
            const float v10 = ft[o00 + WF];
            const float v11 = ft[o00 + WF + 1];
            const float top = v00 + wr_[j] * (v01 - v00);
            const float bot = v10 + wr_[j] * (v11 - v10);
            const float v   = top + hr_[i] * (bot - top);
            cur[j] = v * (fvh[i] * fvw[j]);
        }
        if (i > 0) {
#pragma unroll
            for (int j = 0; j < 7; ++j)
                srow[(i - 1) * 7 + j] =
                    0.25f * (prev[j] + prev[j + 1] + cur[j] + cur[j + 1]);
        }
#pragma unroll
        for (int j = 0; j < 8; ++j) prev[j] = cur[j];
    }
    __syncthreads();
    float* obase = out + ((size_t)k * CCH + (size_t)chunk * 256) * 49;
    const f32x4* s4 = reinterpret_cast<const f32x4*>(sbuf);
    f32x4*       o4 = reinterpret_cast<f32x4*>(obase);
    for (int idx = tid; idx < 3136; idx += 256) o4[idx] = s4[idx];
}

extern "C" void kernel_launch(void* const* d_in, const int* in_sizes, int n_in,
                              void* d_out, int out_size, void* d_ws, size_t ws_size,
                              hipStream_t stream) {
    const float* feat = (const float*)d_in[0];
    const float* rois = (const float*)d_in[1];
    float*       out  = (float*)d_out;

    const int B = in_sizes[0] / (CCH * HF * WF);
    const int K = in_sizes[1] / 5;

    const size_t tbytes = (size_t)B * CCH * HF * WF * sizeof(unsigned short);
    if (ws_size >= tbytes) {
        unsigned short* ftr = (unsigned short*)d_ws;
        dim3 tg((HF * WF) / 32, CCH / 32, B);
        nchw_to_nhwc_bf16<<<tg, 256, 0, stream>>>(feat, ftr);
        roialign_bf16<<<K * 2, 256, 0, stream>>>(ftr, rois, out);
    } else {
        roialign_f32_nchw<<<K * 2, 256, 0, stream>>>(feat, rois, out);
    }
}

// Round 9
// 70.016 us; speedup vs baseline: 2.7906x; 2.7906x over previous
//
#include <hip/hip_runtime.h>

#define HF 64
#define WF 64
#define CCH 512

typedef float f32x4 __attribute__((ext_vector_type(4)));

// f32 -> bf16 round-to-nearest-even
__device__ __forceinline__ unsigned short f32_to_bf16(float f) {
    unsigned int x = __float_as_uint(f);
    unsigned int r = (x + 0x7FFFu + ((x >> 16) & 1u)) >> 16;
    return (unsigned short)r;
}
__device__ __forceinline__ float bf16_to_f32(unsigned short u) {
    return __uint_as_float(((unsigned int)u) << 16);
}

// ---------------- transpose+convert NCHW f32 -> NHWC bf16 -------------------
__global__ __launch_bounds__(256) void nchw_to_nhwc_bf16(const float* __restrict__ src,
                                                         unsigned short* __restrict__ dst) {
    __shared__ float tile[32][33];
    const int hw0 = blockIdx.x * 32;
    const int c0  = blockIdx.y * 32;
    const int b   = blockIdx.z;
    const int tx  = threadIdx.x & 31;
    const int ty  = threadIdx.x >> 5;   // 0..7
    const float*    s = src + (size_t)b * CCH * (HF * WF);
    unsigned short* d = dst + (size_t)b * (HF * WF) * CCH;
#pragma unroll
    for (int i = 0; i < 32; i += 8)
        tile[ty + i][tx] = s[(size_t)(c0 + ty + i) * (HF * WF) + hw0 + tx];
    __syncthreads();
#pragma unroll
    for (int i = 0; i < 32; i += 8)
        d[(size_t)(hw0 + ty + i) * CCH + c0 + tx] = f32_to_bf16(tile[tx][ty + i]);
}

// ---------------- main RoIAlign+avg kernel (NHWC bf16 gather) ---------------
// One block = (roi k, channel chunk of 256). Thread = one channel.
// LEDGER of hard-won constraints:
//  - R5: NEVER stage output as bf16 in LDS (73->444us, mechanism unknown).
//  - R8: stores MUST be full-line wave-contiguous. Scalar stores at 196B
//    stride caused RFO: FETCH_SIZE 114MB, 195us. LDS f32 staging is mandatory.
//  - R7: nt stores on output: small win (keep). L2-eviction theory: dead.
//  - f32 LDS staging = 12.5 KB/wave -> 12 waves/CU, split-invariant.
// R9 single change vs R7: wave-private staging + writeout, NO __syncthreads.
// Wave w owns channels [64w,64w+64); its output region is 196 full cache
// lines, written by itself right after filling its LDS quarter. Removes the
// block-wide rendezvous so waves de-phase (gathers and stores overlap).
__global__ __launch_bounds__(256) void roialign_bf16(const unsigned short* __restrict__ ft,
                                                     const float* __restrict__ rois,
                                                     float* __restrict__ out) {
    __shared__ __align__(16) float sbuf[256 * 49];

    const int blk   = blockIdx.x;
    const int k     = blk >> 1;
    const int chunk = blk & 1;
    const int tid   = threadIdx.x;
    const int c     = chunk * 256 + tid;

    const float* r = rois + (size_t)k * 5;
    const int   b  = (int)r[0];
    const float x1 = r[1] * 0.0625f;
    const float y1 = r[2] * 0.0625f;
    const float x2 = r[3] * 0.0625f;
    const float y2 = r[4] * 0.0625f;
    const float bin_h = fmaxf(y2 - y1, 0.0f) / 7.0f;
    const float bin_w = fmaxf(x2 - x1, 0.0f) / 7.0f;

    int   hi_[8]; float hr_[8]; float fvh[8];
    int   wi_[8]; float wr_[8]; float fvw[8];
#pragma unroll
    for (int i = 0; i < 8; ++i) {
        float h  = y1 + (float)i * bin_h;
        float hs = fminf(floorf(h), 62.0f);
        hr_[i]   = h - hs;
        hi_[i]   = (int)fminf(fmaxf(hs, 0.0f), 62.0f);
        fvh[i]   = (h >= 0.0f && h < 64.0f) ? 1.0f : 0.0f;
        float w  = x1 + (float)i * bin_w;
        float ws = fminf(floorf(w), 62.0f);
        wr_[i]   = w - ws;
        wi_[i]   = (int)fminf(fmaxf(ws, 0.0f), 62.0f);
        fvw[i]   = (w >= 0.0f && w < 64.0f) ? 1.0f : 0.0f;
    }

    float  prev[8];
    float* srow = sbuf + tid * 49;

#pragma unroll
    for (int i = 0; i < 8; ++i) {
        float cur[8];
#pragma unroll
        for (int j = 0; j < 8; ++j) {
            const unsigned int o00 =
                (unsigned int)(((b * HF + hi_[i]) * WF + wi_[j]) * CCH + c);
            const float v00 = bf16_to_f32(ft[o00]);
            const float v01 = bf16_to_f32(ft[o00 + CCH]);
            const float v10 = bf16_to_f32(ft[o00 + WF * CCH]);
            const float v11 = bf16_to_f32(ft[o00 + WF * CCH + CCH]);
            const float top = v00 + wr_[j] * (v01 - v00);
            const float bot = v10 + wr_[j] * (v11 - v10);
            const float v   = top + hr_[i] * (bot - top);
            cur[j] = v * (fvh[i] * fvw[j]);
        }
        if (i > 0) {
#pragma unroll
            for (int j = 0; j < 7; ++j)
                srow[(i - 1) * 7 + j] =
                    0.25f * (prev[j] + prev[j + 1] + cur[j] + cur[j + 1]);
        }
#pragma unroll
        for (int j = 0; j < 8; ++j) prev[j] = cur[j];
    }

    // Wave-private writeout: no __syncthreads. Wave w wrote LDS range
    // [w*64*49, (w+1)*64*49) floats; it alone reads that range back.
    // Cross-lane-within-wave only -> wave-synchronous, LDS ordering via
    // lgkmcnt. wave_barrier() pins instruction order for the compiler.
    __builtin_amdgcn_wave_barrier();

    const int wid  = tid >> 6;
    const int lane = tid & 63;
    float* obase = out + ((size_t)k * CCH + (size_t)chunk * 256 + (size_t)wid * 64) * 49;
    const f32x4* s4 = reinterpret_cast<const f32x4*>(sbuf + (size_t)wid * 64 * 49);
    f32x4*       o4 = reinterpret_cast<f32x4*>(obase);
    // 64 ch * 49 f32 = 12544 B = 784 f32x4 per wave
    for (int idx = lane; idx < 784; idx += 64)
        __builtin_nontemporal_store(s4[idx], &o4[idx]);
}

// ---------------- fallback: direct NCHW f32 (if ws too small) ---------------
__global__ __launch_bounds__(256) void roialign_f32_nchw(const float* __restrict__ ft,
                                                         const float* __restrict__ rois,
                                                         float* __restrict__ out) {
    __shared__ __align__(16) float sbuf[256 * 49];
    const int blk   = blockIdx.x;
    const int k     = blk >> 1;
    const int chunk = blk & 1;
    const int tid   = threadIdx.x;
    const int c     = chunk * 256 + tid;

    const float* r = rois + (size_t)k * 5;
    const int   b  = (int)r[0];
    const float x1 = r[1] * 0.0625f;
    const float y1 = r[2] * 0.0625f;
    const float x2 = r[3] * 0.0625f;
    const float y2 = r[4] * 0.0625f;
    const float bin_h = fmaxf(y2 - y1, 0.0f) / 7.0f;
    const float bin_w = fmaxf(x2 - x1, 0.0f) / 7.0f;

    int hi_[8]; float hr_[8]; float fvh[8];
    int wi_[8]; float wr_[8]; float fvw[8];
#pragma unroll
    for (int i = 0; i < 8; ++i) {
        float h  = y1 + (float)i * bin_h;
        float hs = fminf(floorf(h), 62.0f);
        hr_[i] = h - hs;
        hi_[i] = (int)fminf(fmaxf(hs, 0.0f), 62.0f);
        fvh[i] = (h >= 0.0f && h < 64.0f) ? 1.0f : 0.0f;
        float w  = x1 + (float)i * bin_w;
        float ws = fminf(floorf(w), 62.0f);
        wr_[i] = w - ws;
        wi_[i] = (int)fminf(fmaxf(ws, 0.0f), 62.0f);
        fvw[i] = (w >= 0.0f && w < 64.0f) ? 1.0f : 0.0f;
    }

    float prev[8];
    float* srow = sbuf + tid * 49;
#pragma unroll
    for (int i = 0; i < 8; ++i) {
        float cur[8];
#pragma unroll
        for (int j = 0; j < 8; ++j) {
            size_t o00 = (size_t)(b * CCH + c) * (HF * WF) + hi_[i] * WF + wi_[j];
            const float v00 = ft[o00];
            const float v01 = ft[o00 + 1];
            const float v10 = ft[o00 + WF];
            const float v11 = ft[o00 + WF + 1];
            const float top = v00 + wr_[j] * (v01 - v00);
            const float bot = v10 + wr_[j] * (v11 - v10);
            const float v   = top + hr_[i] * (bot - top);
            cur[j] = v * (fvh[i] * fvw[j]);
        }
        if (i > 0) {
#pragma unroll
            for (int j = 0; j < 7; ++j)
                srow[(i - 1) * 7 + j] =
                    0.25f * (prev[j] + prev[j + 1] + cur[j] + cur[j + 1]);
        }
#pragma unroll
        for (int j = 0; j < 8; ++j) prev[j] = cur[j];
    }
    __syncthreads();
    float* obase = out + ((size_t)k * CCH + (size_t)chunk * 256) * 49;
    const f32x4* s4 = reinterpret_cast<const f32x4*>(sbuf);
    f32x4*       o4 = reinterpret_cast<f32x4*>(obase);
    for (int idx = tid; idx < 3136; idx += 256) o4[idx] = s4[idx];
}

extern "C" void kernel_launch(void* const* d_in, const int* in_sizes, int n_in,
                              void* d_out, int out_size, void* d_ws, size_t ws_size,
                              hipStream_t stream) {
    const float* feat = (const float*)d_in[0];
    const float* rois = (const float*)d_in[1];
    float*       out  = (float*)d_out;

    const int B = in_sizes[0] / (CCH * HF * WF);
    const int K = in_sizes[1] / 5;

    const size_t tbytes = (size_t)B * CCH * HF * WF * sizeof(unsigned short);
    if (ws_size >= tbytes) {
        unsigned short* ftr = (unsigned short*)d_ws;
        dim3 tg((HF * WF) / 32, CCH / 32, B);
        nchw_to_nhwc_bf16<<<tg, 256, 0, stream>>>(feat, ftr);
        roialign_bf16<<<K * 2, 256, 0, stream>>>(ftr, rois, out);
    } else {
        roialign_f32_nchw<<<K * 2, 256, 0, stream>>>(feat, rois, out);
    }
}

// Round 10
// 66.691 us; speedup vs baseline: 2.9298x; 1.0499x over previous
//
#include <hip/hip_runtime.h>

#define HF 64
#define WF 64
#define CCH 512

typedef float f32x4 __attribute__((ext_vector_type(4)));

// f32 -> bf16 round-to-nearest-even
__device__ __forceinline__ unsigned short f32_to_bf16(float f) {
    unsigned int x = __float_as_uint(f);
    unsigned int r = (x + 0x7FFFu + ((x >> 16) & 1u)) >> 16;
    return (unsigned short)r;
}
__device__ __forceinline__ float bf16_to_f32(unsigned short u) {
    return __uint_as_float(((unsigned int)u) << 16);
}

// ---------------- transpose+convert NCHW f32 -> NHWC bf16 -------------------
__global__ __launch_bounds__(256) void nchw_to_nhwc_bf16(const float* __restrict__ src,
                                                         unsigned short* __restrict__ dst) {
    __shared__ float tile[32][33];
    const int hw0 = blockIdx.x * 32;
    const int c0  = blockIdx.y * 32;
    const int b   = blockIdx.z;
    const int tx  = threadIdx.x & 31;
    const int ty  = threadIdx.x >> 5;   // 0..7
    const float*    s = src + (size_t)b * CCH * (HF * WF);
    unsigned short* d = dst + (size_t)b * (HF * WF) * CCH;
#pragma unroll
    for (int i = 0; i < 32; i += 8)
        tile[ty + i][tx] = s[(size_t)(c0 + ty + i) * (HF * WF) + hw0 + tx];
    __syncthreads();
#pragma unroll
    for (int i = 0; i < 32; i += 8)
        d[(size_t)(hw0 + ty + i) * CCH + c0 + tx] = f32_to_bf16(tile[tx][ty + i]);
}

// ---------------- main RoIAlign+avg kernel (NHWC bf16 gather) ---------------
// LEDGER of hard-won constraints:
//  - R5: NEVER stage output as bf16 in LDS (73->444us, mechanism unknown).
//  - R8: stores MUST be full-line wave-contiguous. Scalar 196B-stride stores
//    caused RFO (FETCH 114MB, 195us). f32 LDS staging is mandatory.
//  - f32 staging => 835 channel-slots/CU (160KB/196B): occupancy reshuffles
//    (R8 occ=38%, R9 de-phase) are neutral. nt stores: small win, keep.
// R10 single change vs R9: row-reuse gather dedup. hi_ is non-decreasing and
// block-uniform; keep corner rows T(=hi) and B(=hi+1) in registers (static
// arrays, uniform branches only). Per i-step load 0, 1, or 2 rows instead of
// always 4 corners x 8 j. Expected gather instrs/bytes: ~-55%.
__global__ __launch_bounds__(256) void roialign_bf16(const unsigned short* __restrict__ ft,
                                                     const float* __restrict__ rois,
                                                     float* __restrict__ out) {
    __shared__ __align__(16) float sbuf[256 * 49];

    const int blk   = blockIdx.x;
    const int k     = blk >> 1;
    const int chunk = blk & 1;
    const int tid   = threadIdx.x;
    const int c     = chunk * 256 + tid;

    const float* r = rois + (size_t)k * 5;
    const int   b  = (int)r[0];
    const float x1 = r[1] * 0.0625f;
    const float y1 = r[2] * 0.0625f;
    const float x2 = r[3] * 0.0625f;
    const float y2 = r[4] * 0.0625f;
    const float bin_h = fmaxf(y2 - y1, 0.0f) / 7.0f;
    const float bin_w = fmaxf(x2 - x1, 0.0f) / 7.0f;

    int   hi_[8]; float hr_[8]; float fvh[8];
    int   wi_[8]; float wr_[8]; float fvw[8];
    unsigned colc[8];
#pragma unroll
    for (int i = 0; i < 8; ++i) {
        float h  = y1 + (float)i * bin_h;
        float hs = fminf(floorf(h), 62.0f);
        hr_[i]   = h - hs;
        hi_[i]   = (int)fminf(fmaxf(hs, 0.0f), 62.0f);
        fvh[i]   = (h >= 0.0f && h < 64.0f) ? 1.0f : 0.0f;
        float w  = x1 + (float)i * bin_w;
        float ws = fminf(floorf(w), 62.0f);
        wr_[i]   = w - ws;
        wi_[i]   = (int)fminf(fmaxf(ws, 0.0f), 62.0f);
        fvw[i]   = (w >= 0.0f && w < 64.0f) ? 1.0f : 0.0f;
        colc[i]  = (unsigned)(wi_[i] * CCH + c);
    }
    const unsigned bBase = (unsigned)(b * HF * WF * CCH);

    // corner-row register caches: T = feature row hi_[i], B = row hi_[i]+1
    float TL[8], TR[8], BL[8], BR[8];
    int curR = -1000;

    float  prev[8];
    float* srow = sbuf + tid * 49;

#pragma unroll
    for (int i = 0; i < 8; ++i) {
        const int rr = hi_[i];
        if (rr == curR) {
            // both rows cached — no loads
        } else if (rr == curR + 1) {
            // shift: old bottom row becomes top; load one new row
#pragma unroll
            for (int j = 0; j < 8; ++j) { TL[j] = BL[j]; TR[j] = BR[j]; }
            const unsigned rb = bBase + (unsigned)((rr + 1) * WF * CCH);
#pragma unroll
            for (int j = 0; j < 8; ++j) {
                BL[j] = bf16_to_f32(ft[rb + colc[j]]);
                BR[j] = bf16_to_f32(ft[rb + colc[j] + CCH]);
            }
        } else {
            const unsigned rt = bBase + (unsigned)(rr * WF * CCH);
            const unsigned rb = rt + (unsigned)(WF * CCH);
#pragma unroll
            for (int j = 0; j < 8; ++j) {
                TL[j] = bf16_to_f32(ft[rt + colc[j]]);
                TR[j] = bf16_to_f32(ft[rt + colc[j] + CCH]);
            }
#pragma unroll
            for (int j = 0; j < 8; ++j) {
                BL[j] = bf16_to_f32(ft[rb + colc[j]]);
                BR[j] = bf16_to_f32(ft[rb + colc[j] + CCH]);
            }
        }
        curR = rr;

        float cur[8];
#pragma unroll
        for (int j = 0; j < 8; ++j) {
            const float top = TL[j] + wr_[j] * (TR[j] - TL[j]);
            const float bot = BL[j] + wr_[j] * (BR[j] - BL[j]);
            const float v   = top + hr_[i] * (bot - top);
            cur[j] = v * (fvh[i] * fvw[j]);
        }
        if (i > 0) {
#pragma unroll
            for (int j = 0; j < 7; ++j)
                srow[(i - 1) * 7 + j] =
                    0.25f * (prev[j] + prev[j + 1] + cur[j] + cur[j + 1]);
        }
#pragma unroll
        for (int j = 0; j < 8; ++j) prev[j] = cur[j];
    }

    // Wave-private writeout (R9): no __syncthreads; wave w reads back only
    // its own LDS quarter. wave_barrier pins ordering for the compiler.
    __builtin_amdgcn_wave_barrier();

    const int wid  = tid >> 6;
    const int lane = tid & 63;
    float* obase = out + ((size_t)k * CCH + (size_t)chunk * 256 + (size_t)wid * 64) * 49;
    const f32x4* s4 = reinterpret_cast<const f32x4*>(sbuf + (size_t)wid * 64 * 49);
    f32x4*       o4 = reinterpret_cast<f32x4*>(obase);
    // 64 ch * 49 f32 = 784 f32x4 per wave
    for (int idx = lane; idx < 784; idx += 64)
        __builtin_nontemporal_store(s4[idx], &o4[idx]);
}

// ---------------- fallback: direct NCHW f32 (if ws too small) ---------------
__global__ __launch_bounds__(256) void roialign_f32_nchw(const float* __restrict__ ft,
                                                         const float* __restrict__ rois,
                                                         float* __restrict__ out) {
    __shared__ __align__(16) float sbuf[256 * 49];
    const int blk   = blockIdx.x;
    const int k     = blk >> 1;
    const int chunk = blk & 1;
    const int tid   = threadIdx.x;
    const int c     = chunk * 256 + tid;

    const float* r = rois + (size_t)k * 5;
    const int   b  = (int)r[0];
    const float x1 = r[1] * 0.0625f;
    const float y1 = r[2] * 0.0625f;
    const float x2 = r[3] * 0.0625f;
    const float y2 = r[4] * 0.0625f;
    const float bin_h = fmaxf(y2 - y1, 0.0f) / 7.0f;
    const float bin_w = fmaxf(x2 - x1, 0.0f) / 7.0f;

    int hi_[8]; float hr_[8]; float fvh[8];
    int wi_[8]; float wr_[8]; float fvw[8];
#pragma unroll
    for (int i = 0; i < 8; ++i) {
        float h  = y1 + (float)i * bin_h;
        float hs = fminf(floorf(h), 62.0f);
        hr_[i] = h - hs;
        hi_[i] = (int)fminf(fmaxf(hs, 0.0f), 62.0f);
        fvh[i] = (h >= 0.0f && h < 64.0f) ? 1.0f : 0.0f;
        float w  = x1 + (float)i * bin_w;
        float ws = fminf(floorf(w), 62.0f);
        wr_[i] = w - ws;
        wi_[i] = (int)fminf(fmaxf(ws, 0.0f), 62.0f);
        fvw[i] = (w >= 0.0f && w < 64.0f) ? 1.0f : 0.0f;
    }

    float prev[8];
    float* srow = sbuf + tid * 49;
#pragma unroll
    for (int i = 0; i < 8; ++i) {
        float cur[8];
#pragma unroll
        for (int j = 0; j < 8; ++j) {
            size_t o00 = (size_t)(b * CCH + c) * (HF * WF) + hi_[i] * WF + wi_[j];
            const float v00 = ft[o00];
            const float v01 = ft[o00 + 1];
            const float v10 = ft[o00 + WF];
            const float v11 = ft[o00 + WF + 1];
            const float top = v00 + wr_[j] * (v01 - v00);
            const float bot = v10 + wr_[j] * (v11 - v10);
            const float v   = top + hr_[i] * (bot - top);
            cur[j] = v * (fvh[i] * fvw[j]);
        }
        if (i > 0) {
#pragma unroll
            for (int j = 0; j < 7; ++j)
                srow[(i - 1) * 7 + j] =
                    0.25f * (prev[j] + prev[j + 1] + cur[j] + cur[j + 1]);
        }
#pragma unroll
        for (int j = 0; j < 8; ++j) prev[j] = cur[j];
    }
    __syncthreads();
    float* obase = out + ((size_t)k * CCH + (size_t)chunk * 256) * 49;
    const f32x4* s4 = reinterpret_cast<const f32x4*>(sbuf);
    f32x4*       o4 = reinterpret_cast<f32x4*>(obase);
    for (int idx = tid; idx < 3136; idx += 256) o4[idx] = s4[idx];
}

extern "C" void kernel_launch(void* const* d_in, const int* in_sizes, int n_in,
                              void* d_out, int out_size, void* d_ws, size_t ws_size,
                              hipStream_t stream) {
    const float* feat = (const float*)d_in[0];
    const float* rois = (const float*)d_in[1];
    float*       out  = (float*)d_out;

    const int B = in_sizes[0] / (CCH * HF * WF);
    const int K = in_sizes[1] / 5;

    const size_t tbytes = (size_t)B * CCH * HF * WF * sizeof(unsigned short);
    if (ws_size >= tbytes) {
        unsigned short* ftr = (unsigned short*)d_ws;
        dim3 tg((HF * WF) / 32, CCH / 32, B);
        nchw_to_nhwc_bf16<<<tg, 256, 0, stream>>>(feat, ftr);
        roialign_bf16<<<K * 2, 256, 0, stream>>>(ftr, rois, out);
    } else {
        roialign_f32_nchw<<<K * 2, 256, 0, stream>>>(feat, rois, out);
    }
}